// Round 3
// baseline (1266.966 us; speedup 1.0000x reference)
//
#include <hip/hip_runtime.h>
#include <math.h>

// Problem constants (fixed by setup_inputs): B=8,S=4096,H=2048,H2=1024,E=8
#define NTOK 32768
#define HDIM 2048
#define H2DIM 1024
#define NE 8

// Workspace float-area layout (UNCHANGED from R2 — no ws_size gamble):
//   logits[262144] @0, sums[8] @262144, C1[1024] @262160, C2[1024] @263184
#define WS_LOGITS 0
#define WS_SUMS 262144
#define WS_C1 262160
#define WS_C2 263184
#define WS_W1_BYTES 1057024ull

// Output layout in floats: ew[262144], masks[262144], loss[1], usage[8]
// NOTE: masks region doubles as SCRATCH for row stats (sRow@+0, sqRow@+32768)
// between prep_kernel and gemm; route_kernel fully overwrites it afterwards.
#define OUT_MASKS 262144
#define OUT_LOSS 524288
#define OUT_USAGE 524289

typedef _Float16 half8 __attribute__((ext_vector_type(8)));
typedef float floatx16 __attribute__((ext_vector_type(16)));

// split: w1' planes carry wscale=32 (avoids fp16 subnormals); lo planes 4096x.
// acc_total = accH + accL/4096 (folded ONCE at epilogue).
// h = rs*acc_total/32 - rs*mu*C1 + (C2 + b1).
#define H_SCALE 0.03125f

// async global->LDS, 16B per lane; LDS dst = wave-uniform base + lane*16.
#define GLDS16(g, l)                                                   \
  __builtin_amdgcn_global_load_lds(                                    \
      (const __attribute__((address_space(1))) void*)(g),              \
      (__attribute__((address_space(3))) void*)(l), 16, 0, 0)

// ---------------------------------------------------------------------------
// Kernel 0 (prep): fused (a) x row LN-stats (all 8192 blocks, 4 rows each,
// coalesced 1KB/instr reads, 64-lane shfl reduce -> srow/sqrow scratch) and
// (b) original w1prep (blocks 0..255): w1' = lw*w1 -> fp16 hi/lo planes in
// fragment-major layout + C1/C2 + zeroing logits/sums.
// Stats moved OUT of the GEMM hot loop (R2 post-mortem: cvt+stats VALU was
// ~700cyc/stage on the critical path).
// ---------------------------------------------------------------------------
__global__ __launch_bounds__(256) void prep_kernel(
    const float* __restrict__ w1, const float* __restrict__ ln_w,
    const float* __restrict__ ln_b, const float* __restrict__ x,
    _Float16* __restrict__ w1p, float* __restrict__ ws,
    float* __restrict__ srow, float* __restrict__ sqrow) {
  const int tid = threadIdx.x;
  const int lane = tid & 63;

  {  // ---- x row stats: wave handles one row ----
    const int n = blockIdx.x * 4 + (tid >> 6);
    const float4* p = (const float4*)(x + (size_t)n * HDIM);
    float s = 0.f, sq = 0.f;
#pragma unroll
    for (int v = 0; v < 8; ++v) {
      float4 f = p[lane + v * 64];
      s += f.x + f.y + f.z + f.w;
      sq = fmaf(f.x, f.x, sq);
      sq = fmaf(f.y, f.y, sq);
      sq = fmaf(f.z, f.z, sq);
      sq = fmaf(f.w, f.w, sq);
    }
#pragma unroll
    for (int o = 1; o < 64; o <<= 1) {
      s += __shfl_xor(s, o);
      sq += __shfl_xor(sq, o);
    }
    if (lane == 0) {
      srow[n] = s;
      sqrow[n] = sq;
    }
  }

  if (blockIdx.x >= 256) return;

  // ---- original w1prep body ----
  ((float4*)(ws + WS_LOGITS))[blockIdx.x * 256 + tid] =
      make_float4(0.f, 0.f, 0.f, 0.f);
  if (blockIdx.x == 0 && tid < NE) ws[WS_SUMS + tid] = 0.f;

  const int n = blockIdx.x * 4 + (tid >> 6);
  const int kc = tid & 63;
  const float4* src = (const float4*)(w1 + (size_t)n * HDIM + kc * 32);
  const float4* lwp = (const float4*)(ln_w + kc * 32);
  const float4* lbp = (const float4*)(ln_b + kc * 32);
  float wv[32], lwv[32], lbv[32];
#pragma unroll
  for (int v = 0; v < 8; ++v) {
    float4 f = src[v], g = lwp[v], h = lbp[v];
    wv[v*4+0]=f.x; wv[v*4+1]=f.y; wv[v*4+2]=f.z; wv[v*4+3]=f.w;
    lwv[v*4+0]=g.x; lwv[v*4+1]=g.y; lwv[v*4+2]=g.z; lwv[v*4+3]=g.w;
    lbv[v*4+0]=h.x; lbv[v*4+1]=h.y; lbv[v*4+2]=h.z; lbv[v*4+3]=h.w;
  }
  float c1 = 0.f, c2 = 0.f;
  _Float16 hi[32], lo[32];
#pragma unroll
  for (int v = 0; v < 32; ++v) {
    float wp = wv[v] * lwv[v];        // fold LN scale into w1
    c1 += wp;
    c2 += lbv[v] * wv[v];             // fold LN bias term
    float t = wp * 32.0f;
    hi[v] = (_Float16)t;
    lo[v] = (_Float16)((t - (float)hi[v]) * 4096.0f);
  }
  // fragment-major store: chunk(nb,kc) + t*1024 + plane*512 + fq*256 + ln*8
  _Float16* dst = w1p + ((size_t)(n >> 5) * 64 + kc) * 2048;
  const int ln8 = (n & 31) * 8;
#pragma unroll
  for (int st = 0; st < 2; ++st)
#pragma unroll
    for (int f = 0; f < 2; ++f) {
      const int b = st * 16 + f * 8;
      half8 h = {hi[b+0],hi[b+1],hi[b+2],hi[b+3],hi[b+4],hi[b+5],hi[b+6],hi[b+7]};
      half8 l = {lo[b+0],lo[b+1],lo[b+2],lo[b+3],lo[b+4],lo[b+5],lo[b+6],lo[b+7]};
      *(half8*)&dst[st * 1024 + 0 + f * 256 + ln8] = h;
      *(half8*)&dst[st * 1024 + 512 + f * 256 + ln8] = l;
    }
#pragma unroll
  for (int o = 1; o < 64; o <<= 1) {
    c1 += __shfl_xor(c1, o);
    c2 += __shfl_xor(c2, o);
  }
  if (kc == 0) {
    ws[WS_C1 + n] = c1;
    ws[WS_C2 + n] = c2;
  }
}

// ---------------------------------------------------------------------------
// Kernel 1 (MFMA): R3 restructure — DEEP GLDS PIPELINE (T3+T4 shape).
// R2 post-mortem: barrier-free register-dataflow plateaued at 955us because
// (a) cvt VALU ~700cyc/stage on critical path, (b) prefetch depth 1 with
// 2 waves/SIMD can't hide ~900cyc HBM latency, (c) reg footprint blocks both
// deeper prefetch and more waves. Fix: pipeline depth in the GLDS queue
// (zero VGPR cost):
//  - 4-slot LDS ring, half-step granularity (16 k): A f32 8KB + B f16 8KB.
//  - 3 half-steps prefetched ahead; steady-state s_waitcnt vmcnt(8) (never
//    0 until drain) + one raw s_barrier per half-step (12 MFMA between).
//  - A staged from x via GLDS with PRE-SWIZZLED per-lane global source
//    (linear LDS dst, XOR-spread rows across 16B slots -> ~conflict-free
//    stride-64B ds_reads). hi/lo split in-register post-ds_read.
//  - B unchanged fragment-major GLDS (lane-contiguous 1KB, conflict-free).
//  - LN stats preloaded from prep kernel's srow/sqrow (no in-loop stats).
// ---------------------------------------------------------------------------
#define STAGE(h)                                                              \
  {                                                                           \
    char* sp = ringc + (((h) & 3) * 16384);                                   \
    GLDS16(aS0 + (size_t)(h) * 64, sp + (2 * wid) * 1024);                    \
    GLDS16(aS1 + (size_t)(h) * 64, sp + (2 * wid + 1) * 1024);                \
    GLDS16(bS0 + (size_t)(h) * 2048, sp + 8192 + wid * 2048);                 \
    GLDS16(bS1 + (size_t)(h) * 2048, sp + 8192 + wid * 2048 + 1024);          \
  }

#define CVTI(f0, f1, ah, al)                                                  \
  {                                                                           \
    float xa[8] = {f0.x, f0.y, f0.z, f0.w, f1.x, f1.y, f1.z, f1.w};           \
    _Pragma("unroll") for (int v = 0; v < 8; ++v) {                           \
      ah[v] = (_Float16)xa[v];                                                \
      al[v] = (_Float16)((xa[v] - (float)ah[v]) * 4096.0f);                   \
    }                                                                         \
  }

#define STEPBODY(h, VM, DOSTAGE)                                              \
  {                                                                           \
    asm volatile("s_waitcnt vmcnt(" #VM ")" ::: "memory");                    \
    __builtin_amdgcn_s_barrier();                                             \
    __builtin_amdgcn_sched_barrier(0);                                        \
    if (DOSTAGE) STAGE((h) + 3);                                              \
    __builtin_amdgcn_sched_barrier(0);                                        \
    const char* As = ringc + ((h) & 3) * 16384;                               \
    const char* Bs = As + 8192;                                               \
    float4 a00 = *(const float4*)(As + aof00);                                \
    float4 a01 = *(const float4*)(As + aof01);                                \
    float4 a10 = *(const float4*)(As + aof10);                                \
    float4 a11 = *(const float4*)(As + aof11);                                \
    half8 bh0 = *(const half8*)(Bs + bof0);                                   \
    half8 bl0 = *(const half8*)(Bs + bof0 + 1024);                            \
    half8 bh1 = *(const half8*)(Bs + bof1);                                   \
    half8 bl1 = *(const half8*)(Bs + bof1 + 1024);                            \
    half8 ah0, al0, ah1, al1;                                                 \
    CVTI(a00, a01, ah0, al0);                                                 \
    CVTI(a10, a11, ah1, al1);                                                 \
    __builtin_amdgcn_s_setprio(1);                                            \
    acc[0][0] = __builtin_amdgcn_mfma_f32_32x32x16_f16(ah0, bh0, acc[0][0], 0, 0, 0);   \
    accL[0][0] = __builtin_amdgcn_mfma_f32_32x32x16_f16(ah0, bl0, accL[0][0], 0, 0, 0); \
    accL[0][0] = __builtin_amdgcn_mfma_f32_32x32x16_f16(al0, bh0, accL[0][0], 0, 0, 0); \
    acc[0][1] = __builtin_amdgcn_mfma_f32_32x32x16_f16(ah0, bh1, acc[0][1], 0, 0, 0);   \
    accL[0][1] = __builtin_amdgcn_mfma_f32_32x32x16_f16(ah0, bl1, accL[0][1], 0, 0, 0); \
    accL[0][1] = __builtin_amdgcn_mfma_f32_32x32x16_f16(al0, bh1, accL[0][1], 0, 0, 0); \
    acc[1][0] = __builtin_amdgcn_mfma_f32_32x32x16_f16(ah1, bh0, acc[1][0], 0, 0, 0);   \
    accL[1][0] = __builtin_amdgcn_mfma_f32_32x32x16_f16(ah1, bl0, accL[1][0], 0, 0, 0); \
    accL[1][0] = __builtin_amdgcn_mfma_f32_32x32x16_f16(al1, bh0, accL[1][0], 0, 0, 0); \
    acc[1][1] = __builtin_amdgcn_mfma_f32_32x32x16_f16(ah1, bh1, acc[1][1], 0, 0, 0);   \
    accL[1][1] = __builtin_amdgcn_mfma_f32_32x32x16_f16(ah1, bl1, accL[1][1], 0, 0, 0); \
    accL[1][1] = __builtin_amdgcn_mfma_f32_32x32x16_f16(al1, bh1, accL[1][1], 0, 0, 0); \
    __builtin_amdgcn_s_setprio(0);                                            \
  }

__global__ __launch_bounds__(256, 2) void gemm_mfma_kernel(
    const float* __restrict__ x, const _Float16* __restrict__ w1p,
    const float* __restrict__ bias1, const float* __restrict__ w2,
    const float* __restrict__ C1, const float* __restrict__ C2,
    const float* __restrict__ srow, const float* __restrict__ sqrow,
    float* __restrict__ logits) {
  __shared__ __align__(16) char ring[4][16384];  // [slot]: A f32 8KB | B f16 8KB
  __shared__ float sRowL[128], sqRowL[128];

  const int tid = threadIdx.x;
  // XCD swizzle: XCD x owns m-tiles [x*32, x*32+32); n varies fastest.
  const int lin = blockIdx.x;
  const int xcd = lin & 7, jj = lin >> 3;
  const int m0 = (xcd * 32 + (jj >> 3)) * 128;
  const int n0 = (jj & 7) * 128;

  const int lane = tid & 63;
  const int wid = tid >> 6;
  const int wm = wid >> 1, wn = wid & 1;   // 64x64 quadrant
  const int fr = lane & 31, fq = lane >> 5;

  if (tid < 128) {
    sRowL[tid] = srow[m0 + tid];
    sqRowL[tid] = sqrow[m0 + tid];
  }

  // A staging src (pre-swizzled): instr g=2*wid(+1) covers rows 32*wid..+31;
  // lane l -> row = g*16 + (l>>2), k-sub = (l&3) ^ ((l>>3)&3) (XOR spreads
  // rows across 16B slots; read side applies the same involution).
  const char* aS0 = (const char*)x +
      (size_t)(m0 + 32 * wid + (lane >> 2)) * (HDIM * 4) +
      (((lane & 3) ^ ((lane >> 3) & 3)) << 4);
  const char* aS1 = aS0 + (size_t)16 * (HDIM * 4);
  // B staging src: fragment-major chunk(nb=n0/32+wid, hs) + plane*1KB
  const char* bS0 = (const char*)w1p +
      (size_t)((n0 >> 5) + wid) * 64 * 4096 + lane * 16;
  const char* bS1 = bS0 + 1024;
  char* ringc = &ring[0][0];

  // A frag read offsets (swizzled): row ar=64*wm+32*i+fr, 16B slot
  // q = (fq*2+h) ^ ((fr>>1)&3)
  const int sw = (fr >> 1) & 3;
  const int aof00 = (64 * wm + fr) * 64 + ((((fq << 1) | 0) ^ sw) << 4);
  const int aof01 = (64 * wm + fr) * 64 + ((((fq << 1) | 1) ^ sw) << 4);
  const int aof10 = (64 * wm + 32 + fr) * 64 + ((((fq << 1) | 0) ^ sw) << 4);
  const int aof11 = (64 * wm + 32 + fr) * 64 + ((((fq << 1) | 1) ^ sw) << 4);
  const int bof0 = (2 * wn) * 2048 + lane * 16;
  const int bof1 = (2 * wn + 1) * 2048 + lane * 16;

  floatx16 acc[2][2], accL[2][2];
#pragma unroll
  for (int i = 0; i < 2; ++i)
#pragma unroll
    for (int j = 0; j < 2; ++j)
#pragma unroll
      for (int r = 0; r < 16; ++r) {
        acc[i][j][r] = 0.f;
        accL[i][j][r] = 0.f;
      }

  // prologue: 3 half-steps in flight (12 loads)
  STAGE(0);
  STAGE(1);
  STAGE(2);

#pragma unroll 1
  for (int hs = 0; hs < 125; ++hs) {
    STEPBODY(hs, 8, 1);
  }
  STEPBODY(125, 8, 0);
  STEPBODY(126, 4, 0);
  STEPBODY(127, 0, 0);

  // Epilogue: fold accL once; h = rs*acc/32 - rs*mu*C1 + (C2+b1); exact GELU
  // fp32; partial GEMM2; 32-lane shfl reduce; atomic logits.
  const float inv_sqrt2 = 0.70710678118654752440f;
  const int c = fr;
  const int col0 = n0 + wn * 64 + c;
  const int col1 = col0 + 32;
  float w2r0[NE], w2r1[NE];
#pragma unroll
  for (int e = 0; e < NE; ++e) {
    w2r0[e] = w2[e * H2DIM + col0];
    w2r1[e] = w2[e * H2DIM + col1];
  }
  const float c1a = C1[col0], c1b = C1[col1];
  const float hb0 = C2[col0] + bias1[col0];
  const float hb1 = C2[col1] + bias1[col1];

#pragma unroll
  for (int i = 0; i < 2; ++i)
#pragma unroll
    for (int r = 0; r < 16; ++r) {
      const int lr = wm * 64 + i * 32 + (r & 3) + 8 * (r >> 2) + 4 * fq;
      const float mu_r = sRowL[lr] * (1.0f / HDIM);
      const float var =
          fmaxf(sqRowL[lr] * (1.0f / HDIM) - mu_r * mu_r, 0.0f);
      const float rsr = 1.0f / sqrtf(var + 1e-5f);
      const float nmr = -rsr * mu_r;
      const float a0 = fmaf(accL[i][0][r], (1.0f / 4096.0f), acc[i][0][r]);
      const float a1 = fmaf(accL[i][1][r], (1.0f / 4096.0f), acc[i][1][r]);
      float h0 = fmaf(a0 * H_SCALE, rsr, fmaf(nmr, c1a, hb0));
      float h1 = fmaf(a1 * H_SCALE, rsr, fmaf(nmr, c1b, hb1));
      float g0 = 0.5f * h0 * (1.0f + erff(h0 * inv_sqrt2));
      float g1 = 0.5f * h1 * (1.0f + erff(h1 * inv_sqrt2));
      float pl[NE];
#pragma unroll
      for (int e = 0; e < NE; ++e) pl[e] = fmaf(g0, w2r0[e], g1 * w2r1[e]);
#pragma unroll
      for (int o = 1; o <= 16; o <<= 1)
#pragma unroll
        for (int e = 0; e < NE; ++e) pl[e] += __shfl_xor(pl[e], o);
      if (c == 0) {
        const int row = m0 + lr;
#pragma unroll
        for (int e = 0; e < NE; ++e)
          atomicAdd(&logits[(size_t)row * NE + e], pl[e]);
      }
    }
}

// ---------------------------------------------------------------------------
// Kernel 2: per-token routing (unchanged logic, verified R2-R4).
// ---------------------------------------------------------------------------
__global__ __launch_bounds__(256) void route_kernel(const float* __restrict__ logits,
                                                    const float* __restrict__ b2,
                                                    float* __restrict__ out,
                                                    float* __restrict__ sums) {
  __shared__ float ssum[NE];
  if (threadIdx.x < NE) ssum[threadIdx.x] = 0.f;
  __syncthreads();

  int tok = blockIdx.x * 256 + threadIdx.x;
  const float4* lp = (const float4*)(logits + (size_t)tok * NE);
  float4 l0 = lp[0], l1 = lp[1];
  float lv[NE] = {l0.x, l0.y, l0.z, l0.w, l1.x, l1.y, l1.z, l1.w};
  float ew[NE];
#pragma unroll
  for (int e = 0; e < NE; ++e) {
    float v = (lv[e] + b2[e]) / 0.7f;
    ew[e] = fminf(fmaxf(v, -50.0f), 50.0f);
  }

  int i1 = 0;
  float v1 = ew[0];
#pragma unroll
  for (int e = 1; e < NE; ++e)
    if (ew[e] > v1) { v1 = ew[e]; i1 = e; }
  int i2 = -1;
  float v2 = -1e30f;
#pragma unroll
  for (int e = 0; e < NE; ++e)
    if (e != i1 && ew[e] > v2) { v2 = ew[e]; i2 = e; }

  float t = expf(v2 - v1);
  float sm1 = 1.0f / (1.0f + t);
  float sm2 = t / (1.0f + t);
  float rsum = fmaxf(sm1 + sm2, 1e-6f);
  float m1 = sm1 / rsum, m2 = sm2 / rsum;

  float4* oew = (float4*)(out + (size_t)tok * NE);
  oew[0] = make_float4(ew[0], ew[1], ew[2], ew[3]);
  oew[1] = make_float4(ew[4], ew[5], ew[6], ew[7]);

  float mv[NE];
#pragma unroll
  for (int e = 0; e < NE; ++e)
    mv[e] = (e == i1) ? m1 : ((e == i2) ? m2 : 0.0f);
  float4* om = (float4*)(out + OUT_MASKS + (size_t)tok * NE);
  om[0] = make_float4(mv[0], mv[1], mv[2], mv[3]);
  om[1] = make_float4(mv[4], mv[5], mv[6], mv[7]);

  atomicAdd(&ssum[i1], sm1);
  atomicAdd(&ssum[i2], sm2);
  __syncthreads();
  if (threadIdx.x < NE) atomicAdd(&sums[threadIdx.x], ssum[threadIdx.x]);
}

// ---------------------------------------------------------------------------
// Kernel 3: usage + KL loss (capacity 16384 >> expected ~4096, no drop).
// ---------------------------------------------------------------------------
__global__ void finalize_kernel(const float* __restrict__ sums,
                                float* __restrict__ out) {
  if (threadIdx.x != 0 || blockIdx.x != 0) return;
  float c[NE], tot = 0.f;
  for (int e = 0; e < NE; ++e) {
    c[e] = sums[e];
    tot += c[e];
  }
  float target = 1.0f / NE;
  float lt = logf(target);
  float kl = 0.f;
  for (int e = 0; e < NE; ++e) {
    float u = c[e] / fmaxf(tot, 1e-6f);
    out[OUT_USAGE + e] = u;
    kl += target * (lt - logf(fmaxf(u, 1e-6f)));
  }
  out[OUT_LOSS] = 0.01f * (kl / NE);
}

// ---------------------------------------------------------------------------
extern "C" void kernel_launch(void* const* d_in, const int* in_sizes, int n_in,
                              void* d_out, int out_size, void* d_ws, size_t ws_size,
                              hipStream_t stream) {
  const float* x = (const float*)d_in[0];
  const float* ln_w = (const float*)d_in[1];
  const float* ln_b = (const float*)d_in[2];
  const float* w1 = (const float*)d_in[3];
  const float* b1 = (const float*)d_in[4];
  const float* w2 = (const float*)d_in[5];
  const float* b2 = (const float*)d_in[6];
  float* out = (float*)d_out;
  float* ws = (float*)d_ws;
  _Float16* w1p = (_Float16*)((char*)d_ws + WS_W1_BYTES);
  (void)ws_size;  // need 9.45MB; harness provided >=9.7MB in R3/R4

  // row-stats scratch lives in out's masks region (overwritten by route later)
  float* srow = out + OUT_MASKS;
  float* sqrow = out + OUT_MASKS + NTOK;

  prep_kernel<<<8192, 256, 0, stream>>>(w1, ln_w, ln_b, x, w1p, ws, srow, sqrow);
  gemm_mfma_kernel<<<2048, 256, 0, stream>>>(
      x, w1p, b1, w2, ws + WS_C1, ws + WS_C2, srow, sqrow, ws + WS_LOGITS);
  route_kernel<<<NTOK / 256, 256, 0, stream>>>(ws + WS_LOGITS, b2, out,
                                               ws + WS_SUMS);
  finalize_kernel<<<1, 64, 0, stream>>>(ws + WS_SUMS, out);
}